// Round 1
// baseline (57.359 us; speedup 1.0000x reference)
//
#include <hip/hip_runtime.h>
#include <math.h>

// Problem shape (fixed by setup_inputs): x [B,T,D] fp32, w [D,1], b [1]
#define B  16
#define T  2048
#define D  512
#define NS 64            // segments along T
#define L  (T / NS)      // 32 steps per segment
#define D4 (D / 4)       // 128 float4 per row

// ---------------------------------------------------------------------------
// Kernel 1: s[b,t] = dot(x[b,t,:], w) + bias.  One wave per row.
// ---------------------------------------------------------------------------
__global__ __launch_bounds__(256) void score_kernel(const float* __restrict__ x,
                                                    const float* __restrict__ w,
                                                    const float* __restrict__ bias,
                                                    float* __restrict__ s) {
    int row  = blockIdx.x * 4 + (threadIdx.x >> 6);   // 4 waves/block
    int lane = threadIdx.x & 63;
    const float4* x4 = (const float4*)(x + (size_t)row * D);
    const float4* w4 = (const float4*)w;
    float4 a0 = x4[lane];
    float4 a1 = x4[lane + 64];
    float4 b0 = w4[lane];
    float4 b1 = w4[lane + 64];
    float dot = a0.x * b0.x + a0.y * b0.y + a0.z * b0.z + a0.w * b0.w +
                a1.x * b1.x + a1.y * b1.y + a1.z * b1.z + a1.w * b1.w;
#pragma unroll
    for (int off = 32; off > 0; off >>= 1) dot += __shfl_xor(dot, off);
    if (lane == 0) s[row] = dot + bias[0];
}

// ---------------------------------------------------------------------------
// Kernel 2: per batch — M = max_t s, p_t = exp(s_t - M), den_t = prefix sum p,
// store p (in place over s) and 1/den.  One 256-thread block per batch,
// 8 consecutive elements per thread, Hillis-Steele block scan.
// ---------------------------------------------------------------------------
__global__ __launch_bounds__(256) void softscan_kernel(float* __restrict__ sp,
                                                       float* __restrict__ invden) {
    int b = blockIdx.x;
    int tid = threadIdx.x, lane = tid & 63, wid = tid >> 6;
    float* s = sp + (size_t)b * T;

    float v[8];
    float mx = -1e30f;
#pragma unroll
    for (int i = 0; i < 8; ++i) {
        v[i] = s[tid * 8 + i];
        mx = fmaxf(mx, v[i]);
    }
#pragma unroll
    for (int off = 32; off > 0; off >>= 1) mx = fmaxf(mx, __shfl_xor(mx, off));
    __shared__ float wred[4];
    if (lane == 0) wred[wid] = mx;
    __syncthreads();
    mx = fmaxf(fmaxf(wred[0], wred[1]), fmaxf(wred[2], wred[3]));

    float ps[8];
    float tot = 0.f;
#pragma unroll
    for (int i = 0; i < 8; ++i) {
        float e = __expf(v[i] - mx);
        tot += e;
        ps[i] = tot;   // within-thread inclusive prefix
        v[i] = e;      // p value
    }

    __shared__ float sc[256];
    sc[tid] = tot;
    __syncthreads();
    for (int off = 1; off < 256; off <<= 1) {
        float t = (tid >= off) ? sc[tid - off] : 0.f;
        __syncthreads();
        sc[tid] += t;
        __syncthreads();
    }
    float excl = sc[tid] - tot;   // exclusive prefix of thread totals

#pragma unroll
    for (int i = 0; i < 8; ++i) {
        float den = excl + ps[i];
        s[tid * 8 + i] = v[i];                          // p
        invden[(size_t)b * T + tid * 8 + i] = 1.0f / den;
    }
}

// ---------------------------------------------------------------------------
// Kernel 3: per (batch, segment): segsum[b,k,:] = sum_{j in seg} p_j * x[b,j,:]
// 128 threads, one float4 of D per thread.
// ---------------------------------------------------------------------------
__global__ __launch_bounds__(128) void segsum_kernel(const float* __restrict__ x,
                                                     const float* __restrict__ p,
                                                     float* __restrict__ segsum) {
    int b = blockIdx.x / NS, k = blockIdx.x % NS;
    int t0 = k * L;
    int d4 = threadIdx.x;
    const float4* x4 = (const float4*)x + ((size_t)b * T + t0) * D4;

    __shared__ float pl[L];
    if (threadIdx.x < L) pl[threadIdx.x] = p[(size_t)b * T + t0 + threadIdx.x];
    __syncthreads();

    float ax = 0.f, ay = 0.f, az = 0.f, aw = 0.f;
#pragma unroll 4
    for (int j = 0; j < L; ++j) {
        float4 xv = x4[(size_t)j * D4 + d4];
        float pj = pl[j];
        ax += pj * xv.x; ay += pj * xv.y; az += pj * xv.z; aw += pj * xv.w;
    }
    float4 r; r.x = ax; r.y = ay; r.z = az; r.w = aw;
    ((float4*)segsum)[((size_t)b * NS + k) * D4 + d4] = r;
}

// ---------------------------------------------------------------------------
// Kernel 4: in-place exclusive prefix over the NS segment vectors, per (b,d4).
// ---------------------------------------------------------------------------
__global__ __launch_bounds__(256) void segscan_kernel(float* __restrict__ segsum) {
    int g = blockIdx.x * blockDim.x + threadIdx.x;   // [0, B*D4)
    int b = g / D4, d4 = g % D4;
    float4* ss = (float4*)segsum + (size_t)b * NS * D4 + d4;
    float ax = 0.f, ay = 0.f, az = 0.f, aw = 0.f;
    for (int k = 0; k < NS; ++k) {
        float4 v = ss[(size_t)k * D4];
        float4 e; e.x = ax; e.y = ay; e.z = az; e.w = aw;
        ss[(size_t)k * D4] = e;                       // exclusive prefix
        ax += v.x; ay += v.y; az += v.z; aw += v.w;
    }
}

// ---------------------------------------------------------------------------
// Kernel 5: per (batch, segment): seeded weighted scan producing outputs.
// out[b,t+1,:] = (seed + running sum p_j x_j) * invden_t ; out[b,0,:] = x[b,0,:]
// ---------------------------------------------------------------------------
__global__ __launch_bounds__(128) void output_kernel(const float* __restrict__ x,
                                                     const float* __restrict__ p,
                                                     const float* __restrict__ invden,
                                                     const float* __restrict__ segsum,
                                                     float* __restrict__ out) {
    int b = blockIdx.x / NS, k = blockIdx.x % NS;
    int t0 = k * L;
    int d4 = threadIdx.x;
    const float4* x4 = (const float4*)x + ((size_t)b * T + t0) * D4;
    float4* out4 = (float4*)out + (size_t)b * T * D4;

    __shared__ float pl[L], il[L];
    if (threadIdx.x < L) {
        pl[threadIdx.x] = p[(size_t)b * T + t0 + threadIdx.x];
        il[threadIdx.x] = invden[(size_t)b * T + t0 + threadIdx.x];
    }
    __syncthreads();

    float4 a = ((const float4*)segsum)[((size_t)b * NS + k) * D4 + d4];
    float ax = a.x, ay = a.y, az = a.z, aw = a.w;

    if (k == 0) {   // passthrough row: out[b,0,:] = x[b,0,:]
        out4[d4] = ((const float4*)x)[(size_t)b * T * D4 + d4];
    }

#pragma unroll 4
    for (int j = 0; j < L; ++j) {
        float4 xv = x4[(size_t)j * D4 + d4];
        float pj = pl[j];
        ax += pj * xv.x; ay += pj * xv.y; az += pj * xv.z; aw += pj * xv.w;
        int t = t0 + j;
        if (t < T - 1) {
            float idn = il[j];
            float4 r; r.x = ax * idn; r.y = ay * idn; r.z = az * idn; r.w = aw * idn;
            out4[(size_t)(t + 1) * D4 + d4] = r;
        }
    }
}

// ---------------------------------------------------------------------------
extern "C" void kernel_launch(void* const* d_in, const int* in_sizes, int n_in,
                              void* d_out, int out_size, void* d_ws, size_t ws_size,
                              hipStream_t stream) {
    const float* x    = (const float*)d_in[0];
    const float* w    = (const float*)d_in[1];
    const float* bias = (const float*)d_in[2];
    float* out = (float*)d_out;

    // workspace layout (fp32): p[B*T] | invden[B*T] | segsum[B*NS*D]
    float* sp     = (float*)d_ws;
    float* invden = sp + (size_t)B * T;
    float* segsum = invden + (size_t)B * T;

    score_kernel  <<<(B * T) / 4, 256, 0, stream>>>(x, w, bias, sp);
    softscan_kernel<<<B,           256, 0, stream>>>(sp, invden);
    segsum_kernel <<<B * NS,       128, 0, stream>>>(x, sp, segsum);
    segscan_kernel<<<(B * D4) / 256, 256, 0, stream>>>(segsum);
    output_kernel <<<B * NS,       128, 0, stream>>>(x, sp, invden, segsum, out);
}

// Round 2
// 41.666 us; speedup vs baseline: 1.3766x; 1.3766x over previous
//
#include <hip/hip_runtime.h>
#include <math.h>

// Problem shape (fixed by setup_inputs): x [B,T,D] fp32, w [D,1], b [1]
#define B  16
#define T  2048
#define D  512
#define NS 64            // segments along T
#define L  (T / NS)      // 32 steps per segment
#define D4 (D / 4)       // 128 float4 per row

// ---------------------------------------------------------------------------
// Kernel A: per (batch, segment) block (256 thr = 4 waves, 8 rows/wave):
//   s_j   = dot(x_j, w) + bias        (row held in registers)
//   m_k   = max_j s_j                 (segment-local max)
//   e_j   = exp(s_j - m_k)            -> p_loc
//   q_k   = sum_j e_j
//   V_k   = sum_j e_j * x_j           (from registers, cross-wave LDS reduce)
// Reads x exactly once.
// ---------------------------------------------------------------------------
__global__ __launch_bounds__(256) void seg_kernel(const float* __restrict__ x,
                                                  const float* __restrict__ w,
                                                  const float* __restrict__ bias,
                                                  float* __restrict__ p_loc,
                                                  float* __restrict__ m_out,
                                                  float* __restrict__ q_out,
                                                  float* __restrict__ V) {
    int b = blockIdx.x / NS, k = blockIdx.x % NS;
    int t0 = k * L;
    int tid = threadIdx.x, lane = tid & 63, wv = tid >> 6;
    const float4* x4 = (const float4*)x + ((size_t)b * T + t0) * D4;
    const float4* w4 = (const float4*)w;
    float4 w0 = w4[lane], w1 = w4[lane + 64];

    float4 xr0[8], xr1[8];
    float dots[8];
#pragma unroll
    for (int r = 0; r < 8; ++r) {
        int j = wv * 8 + r;
        xr0[r] = x4[(size_t)j * D4 + lane];
        xr1[r] = x4[(size_t)j * D4 + lane + 64];
        dots[r] = xr0[r].x * w0.x + xr0[r].y * w0.y + xr0[r].z * w0.z + xr0[r].w * w0.w +
                  xr1[r].x * w1.x + xr1[r].y * w1.y + xr1[r].z * w1.z + xr1[r].w * w1.w;
    }

    __shared__ float s_sh[L], e_sh[L];
    __shared__ float accbuf[4][D];

#pragma unroll
    for (int r = 0; r < 8; ++r) {
        float d = dots[r];
#pragma unroll
        for (int off = 32; off > 0; off >>= 1) d += __shfl_xor(d, off);
        if (lane == 0) s_sh[wv * 8 + r] = d + bias[0];
    }
    __syncthreads();

    float mk = -1e30f;
#pragma unroll
    for (int j = 0; j < L; ++j) mk = fmaxf(mk, s_sh[j]);

    float4 a0 = {0.f, 0.f, 0.f, 0.f}, a1 = {0.f, 0.f, 0.f, 0.f};
#pragma unroll
    for (int r = 0; r < 8; ++r) {
        float e = __expf(s_sh[wv * 8 + r] - mk);
        if (lane == 0) e_sh[wv * 8 + r] = e;
        a0.x += e * xr0[r].x; a0.y += e * xr0[r].y; a0.z += e * xr0[r].z; a0.w += e * xr0[r].w;
        a1.x += e * xr1[r].x; a1.y += e * xr1[r].y; a1.z += e * xr1[r].z; a1.w += e * xr1[r].w;
    }
    ((float4*)accbuf[wv])[lane]      = a0;
    ((float4*)accbuf[wv])[lane + 64] = a1;
    __syncthreads();

    if (tid < 128) {
        float4 s0 = ((float4*)accbuf[0])[tid];
        float4 s1 = ((float4*)accbuf[1])[tid];
        float4 s2 = ((float4*)accbuf[2])[tid];
        float4 s3 = ((float4*)accbuf[3])[tid];
        float4 r;
        r.x = s0.x + s1.x + s2.x + s3.x;
        r.y = s0.y + s1.y + s2.y + s3.y;
        r.z = s0.z + s1.z + s2.z + s3.z;
        r.w = s0.w + s1.w + s2.w + s3.w;
        ((float4*)V)[((size_t)b * NS + k) * D4 + tid] = r;
    }
    if (tid < L) p_loc[(size_t)b * T + t0 + tid] = e_sh[tid];
    if (tid == 0) {
        m_out[b * NS + k] = mk;
        float q = 0.f;
#pragma unroll
        for (int j = 0; j < L; ++j) q += e_sh[j];
        q_out[b * NS + k] = q;
    }
}

// ---------------------------------------------------------------------------
// Kernel B: heterogeneous blocks.
//  blocks [0,B): per batch — M_b, scale_k, exclusive prefix of scale*q ->
//                per-element invden[b,t] and wcoef[b,t] = scale_k * e_t
//  blocks [B, B+B*32): per (batch, 4-wide d4 chunk) — parallel Hillis-Steele
//                exclusive prefix over the 64 segments of scale_k*V_k -> P
// ---------------------------------------------------------------------------
__global__ __launch_bounds__(256) void mid_kernel(const float* __restrict__ p_loc,
                                                  const float* __restrict__ m_in,
                                                  const float* __restrict__ q_in,
                                                  const float* __restrict__ V,
                                                  float* __restrict__ P,
                                                  float* __restrict__ wcoef,
                                                  float* __restrict__ invden) {
    __shared__ float4 buf4[256];
    __shared__ float sm[NS];
    __shared__ float Qsh[NS];
    __shared__ float tsum[256];
    int tid = threadIdx.x;

    if (blockIdx.x < B) {
        int b = blockIdx.x;
        if (tid < 64) {
            float mk = m_in[b * NS + tid];
            float M = mk;
#pragma unroll
            for (int off = 32; off > 0; off >>= 1) M = fmaxf(M, __shfl_xor(M, off));
            float sc = __expf(mk - M);
            float qp = sc * q_in[b * NS + tid];
            float incl = qp;
#pragma unroll
            for (int off = 1; off < 64; off <<= 1) {
                float t = __shfl_up(incl, off);
                if (tid >= off) incl += t;
            }
            sm[tid]  = sc;
            Qsh[tid] = incl - qp;   // exclusive prefix of scaled segment sums
        }
        const float4* pp = (const float4*)(p_loc + (size_t)b * T);
        float4 pv0 = pp[tid * 2], pv1 = pp[tid * 2 + 1];
        float p[8] = {pv0.x, pv0.y, pv0.z, pv0.w, pv1.x, pv1.y, pv1.z, pv1.w};
        float pf[8];
        float run = 0.f;
#pragma unroll
        for (int i = 0; i < 8; ++i) { run += p[i]; pf[i] = run; }
        tsum[tid] = run;
        __syncthreads();
        int g = tid & 3, base = tid & ~3;
        float excl = 0.f;
        if (g > 0) excl += tsum[base + 0];
        if (g > 1) excl += tsum[base + 1];
        if (g > 2) excl += tsum[base + 2];
        int kk = tid >> 2;
        float sc = sm[kk], Q = Qsh[kk];
        float od[8], wc[8];
#pragma unroll
        for (int i = 0; i < 8; ++i) {
            od[i] = 1.0f / (Q + sc * (excl + pf[i]));
            wc[i] = sc * p[i];
        }
        float4* wcp = (float4*)(wcoef + (size_t)b * T) + tid * 2;
        float4* idp = (float4*)(invden + (size_t)b * T) + tid * 2;
        float4 t0v; t0v.x = wc[0]; t0v.y = wc[1]; t0v.z = wc[2]; t0v.w = wc[3];
        float4 t1v; t1v.x = wc[4]; t1v.y = wc[5]; t1v.z = wc[6]; t1v.w = wc[7];
        wcp[0] = t0v; wcp[1] = t1v;
        float4 u0; u0.x = od[0]; u0.y = od[1]; u0.z = od[2]; u0.w = od[3];
        float4 u1; u1.x = od[4]; u1.y = od[5]; u1.z = od[6]; u1.w = od[7];
        idp[0] = u0; idp[1] = u1;
    } else {
        int idx = blockIdx.x - B;
        int b = idx >> 5, c = idx & 31;
        int k = tid >> 2, cc = tid & 3, d4 = c * 4 + cc;
        if (tid < NS) sm[tid] = m_in[b * NS + tid];
        __syncthreads();
        float M = -1e30f;
#pragma unroll
        for (int i = 0; i < NS; ++i) M = fmaxf(M, sm[i]);
        float sc = __expf(sm[k] - M);
        float4 v = ((const float4*)V)[((size_t)b * NS + k) * D4 + d4];
        v.x *= sc; v.y *= sc; v.z *= sc; v.w *= sc;
        buf4[tid] = v;
        __syncthreads();
        float4 run = v;
        for (int off = 1; off < NS; off <<= 1) {
            float4 t = {0.f, 0.f, 0.f, 0.f};
            if (k >= off) t = buf4[tid - 4 * off];
            __syncthreads();
            run.x += t.x; run.y += t.y; run.z += t.z; run.w += t.w;
            buf4[tid] = run;
            __syncthreads();
        }
        float4 ex; ex.x = run.x - v.x; ex.y = run.y - v.y; ex.z = run.z - v.z; ex.w = run.w - v.w;
        ((float4*)P)[((size_t)b * NS + k) * D4 + d4] = ex;
    }
}

// ---------------------------------------------------------------------------
// Kernel C: per (batch, segment): seeded weighted scan producing outputs.
// out[b,t+1,:] = (P_k + sum_{j<=t in seg} wcoef_j * x_j) * invden_t
// out[b,0,:]   = x[b,0,:]
// ---------------------------------------------------------------------------
__global__ __launch_bounds__(128) void output_kernel(const float* __restrict__ x,
                                                     const float* __restrict__ wcoef,
                                                     const float* __restrict__ invden,
                                                     const float* __restrict__ P,
                                                     float* __restrict__ out) {
    int b = blockIdx.x / NS, k = blockIdx.x % NS;
    int t0 = k * L;
    int d4 = threadIdx.x;
    const float4* x4 = (const float4*)x + ((size_t)b * T + t0) * D4;
    float4* out4 = (float4*)out + (size_t)b * T * D4;

    __shared__ float wl[L], il[L];
    if (threadIdx.x < L) {
        wl[threadIdx.x] = wcoef[(size_t)b * T + t0 + threadIdx.x];
        il[threadIdx.x] = invden[(size_t)b * T + t0 + threadIdx.x];
    }
    __syncthreads();

    float4 a = ((const float4*)P)[((size_t)b * NS + k) * D4 + d4];

    if (k == 0) {   // passthrough row: out[b,0,:] = x[b,0,:]
        out4[d4] = ((const float4*)x)[(size_t)b * T * D4 + d4];
    }

#pragma unroll 4
    for (int j = 0; j < L; ++j) {
        float4 xv = x4[(size_t)j * D4 + d4];
        float pj = wl[j];
        a.x += pj * xv.x; a.y += pj * xv.y; a.z += pj * xv.z; a.w += pj * xv.w;
        int t = t0 + j;
        if (t < T - 1) {
            float idn = il[j];
            float4 r; r.x = a.x * idn; r.y = a.y * idn; r.z = a.z * idn; r.w = a.w * idn;
            out4[(size_t)(t + 1) * D4 + d4] = r;
        }
    }
}

// ---------------------------------------------------------------------------
extern "C" void kernel_launch(void* const* d_in, const int* in_sizes, int n_in,
                              void* d_out, int out_size, void* d_ws, size_t ws_size,
                              hipStream_t stream) {
    const float* x    = (const float*)d_in[0];
    const float* w    = (const float*)d_in[1];
    const float* bias = (const float*)d_in[2];
    float* out = (float*)d_out;

    // workspace layout (fp32):
    // p_loc[B*T] | wcoef[B*T] | invden[B*T] | m[B*NS] | q[B*NS] | V[B*NS*D] | P[B*NS*D]
    float* p_loc  = (float*)d_ws;
    float* wcoef  = p_loc  + (size_t)B * T;
    float* invden = wcoef  + (size_t)B * T;
    float* m      = invden + (size_t)B * T;
    float* q      = m      + (size_t)B * NS;
    float* V      = q      + (size_t)B * NS;
    float* P      = V      + (size_t)B * NS * D;

    seg_kernel   <<<B * NS,          256, 0, stream>>>(x, w, bias, p_loc, m, q, V);
    mid_kernel   <<<B + B * (D4/4),  256, 0, stream>>>(p_loc, m, q, V, P, wcoef, invden);
    output_kernel<<<B * NS,          128, 0, stream>>>(x, wcoef, invden, P, out);
}